// Round 1
// baseline (820.517 us; speedup 1.0000x reference)
//
#include <hip/hip_runtime.h>

#define NEG 0.2f
__device__ __forceinline__ float lrelu(float x){ return fmaxf(x, NEG*x); }

// ---------------- CSR build ----------------
__global__ __launch_bounds__(256) void hist_kernel(const int* __restrict__ dstv, int* __restrict__ counts, int E){
  int i = blockIdx.x*256 + threadIdx.x;
  if (i < E) atomicAdd(&counts[dstv[i]], 1);
}

__global__ __launch_bounds__(256) void scan_kernel(const int* __restrict__ counts, int* __restrict__ offs,
                                                   int* __restrict__ cursor, int n){
  __shared__ int wsum[4];
  __shared__ int carry_s;
  int tid = threadIdx.x, lane = tid & 63, wv = tid >> 6;
  if (tid == 0) carry_s = 0;
  __syncthreads();
  const int CH = 2048;
  int nch = (n + CH - 1)/CH;
  for (int ch=0; ch<nch; ++ch){
    int base_i = ch*CH + tid*8;
    int v[8], pre[8];
    #pragma unroll
    for (int j=0;j<8;++j){ int i=base_i+j; v[j]=(i<n)?counts[i]:0; }
    int t=0;
    #pragma unroll
    for (int j=0;j<8;++j){ pre[j]=t; t+=v[j]; }
    int incl=t;
    #pragma unroll
    for (int m=1;m<64;m<<=1){ int u=__shfl_up(incl,m); if(lane>=m) incl+=u; }
    int wexcl = incl - t;
    if (lane==63) wsum[wv]=incl;
    __syncthreads();
    int wbase=0;
    for (int w2=0;w2<wv;++w2) wbase+=wsum[w2];
    int total = wsum[0]+wsum[1]+wsum[2]+wsum[3];
    int base = carry_s + wbase + wexcl;
    #pragma unroll
    for (int j=0;j<8;++j){ int i=base_i+j; if(i<n){ int val=base+pre[j]; offs[i]=val; cursor[i]=val; } }
    __syncthreads();
    if (tid==0) carry_s += total;
    __syncthreads();
  }
  if (tid==0) offs[n]=carry_s;
}

__global__ __launch_bounds__(256) void scatter_kernel(const int* __restrict__ srcv, const int* __restrict__ dstv,
                                                      int* __restrict__ cursor, int* __restrict__ csr, int E){
  int i = blockIdx.x*256 + threadIdx.x;
  if (i < E){ int d=dstv[i]; int p=atomicAdd(&cursor[d],1); csr[p]=srcv[i]; }
}

// ---------------- GEMM: Y[n,NOUT] = X[n,128] @ W[128,NOUT] ----------------
template<int NOUT, int TN>
__global__ __launch_bounds__(256) void gemm_k128(const float* __restrict__ X, const float* __restrict__ W,
                                                 float* __restrict__ Y, int n){
  constexpr int NC = NOUT / TN;     // col groups
  constexpr int RG = 256 / NC;      // row groups
  constexpr int BM = RG * 4;        // rows per block
  __shared__ float Wl[128 * NOUT];
  for (int i = threadIdx.x; i < 128*NOUT/4; i += 256)
    ((float4*)Wl)[i] = ((const float4*)W)[i];
  __syncthreads();
  int cg = threadIdx.x % NC;
  int rg = threadIdx.x / NC;
  int row0 = blockIdx.x * BM + rg * 4;
  float acc[4][TN];
  #pragma unroll
  for (int r=0;r<4;++r)
    #pragma unroll
    for (int c=0;c<TN;++c) acc[r][c]=0.f;
  for (int k4 = 0; k4 < 32; ++k4){
    float4 xv[4];
    #pragma unroll
    for (int r = 0; r < 4; ++r){
      int row = row0 + r;
      xv[r] = (row < n) ? ((const float4*)(X + (size_t)row*128))[k4] : make_float4(0.f,0.f,0.f,0.f);
    }
    #pragma unroll
    for (int kk = 0; kk < 4; ++kk){
      int k = k4*4 + kk;
      float wv[TN];
      #pragma unroll
      for (int c = 0; c < TN; ++c) wv[c] = Wl[k*NOUT + cg*TN + c];
      #pragma unroll
      for (int r = 0; r < 4; ++r){
        float xr = (kk==0)?xv[r].x:(kk==1)?xv[r].y:(kk==2)?xv[r].z:xv[r].w;
        #pragma unroll
        for (int c = 0; c < TN; ++c) acc[r][c] = fmaf(xr, wv[c], acc[r][c]);
      }
    }
  }
  #pragma unroll
  for (int r = 0; r < 4; ++r){
    int row = row0 + r;
    if (row < n){
      #pragma unroll
      for (int c = 0; c < TN; c += 4)
        *(float4*)&Y[(size_t)row*NOUT + cg*TN + c] = make_float4(acc[r][c],acc[r][c+1],acc[r][c+2],acc[r][c+3]);
    }
  }
}

// ---------------- alpha: per-node dot(h, a_src/a_dst) ----------------
__global__ __launch_bounds__(256) void alpha_h4(const float* __restrict__ h, const float* __restrict__ a_s,
                                                const float* __restrict__ a_d, float4* __restrict__ as_,
                                                float4* __restrict__ ad_, int n){
  int wid = (blockIdx.x*256 + threadIdx.x) >> 6;
  int lane = threadIdx.x & 63;
  if (wid >= n) return;
  const float* row = h + (size_t)wid*128;
  float x0 = row[lane], x1 = row[lane+64];
  float s0 = x0*a_s[lane], s1 = x1*a_s[lane+64];
  float d0 = x0*a_d[lane], d1 = x1*a_d[lane+64];
  #pragma unroll
  for (int m=16;m>=1;m>>=1){
    s0 += __shfl_xor(s0,m); s1 += __shfl_xor(s1,m);
    d0 += __shfl_xor(d0,m); d1 += __shfl_xor(d1,m);
  }
  float h0s=__shfl(s0,0), h1s=__shfl(s0,32), h2s=__shfl(s1,0), h3s=__shfl(s1,32);
  float h0d=__shfl(d0,0), h1d=__shfl(d0,32), h2d=__shfl(d1,0), h3d=__shfl(d1,32);
  if (lane==0){ as_[wid]=make_float4(h0s,h1s,h2s,h3s); ad_[wid]=make_float4(h0d,h1d,h2d,h3d); }
}

__global__ __launch_bounds__(256) void alpha_h1(const float* __restrict__ h, const float* __restrict__ a_s,
                                                const float* __restrict__ a_d, float* __restrict__ as_,
                                                float* __restrict__ ad_, int n){
  int wid = (blockIdx.x*256 + threadIdx.x) >> 6;
  int lane = threadIdx.x & 63;
  if (wid >= n) return;
  float s=0.f, d=0.f;
  if (lane < 32){ float x = h[(size_t)wid*32 + lane]; s = x*a_s[lane]; d = x*a_d[lane]; }
  #pragma unroll
  for (int m=16;m>=1;m>>=1){ s += __shfl_xor(s,m); d += __shfl_xor(d,m); }
  if (lane==0){ as_[wid]=s; ad_[wid]=d; }
}

// ---------------- aggregation, 4 heads x 32 ch ----------------
__global__ __launch_bounds__(256) void agg_h4(const float* __restrict__ hin,
    const float4* __restrict__ as_, const float4* __restrict__ ad_,
    const int* __restrict__ offs, const int* __restrict__ csr,
    const float* __restrict__ bias, float* __restrict__ hout, int n){
  int wid = (blockIdx.x*256 + threadIdx.x) >> 6;
  int lane = threadIdx.x & 63;
  if (wid >= n) return;
  const int d = wid;
  float4 ad4 = ad_[d];
  float4 asd = as_[d];
  int r0 = offs[d], r1 = offs[d+1];
  // pass 1: per-head max (lane-parallel over edges), incl. self-loop
  float m0 = lrelu(asd.x+ad4.x), m1 = lrelu(asd.y+ad4.y);
  float m2 = lrelu(asd.z+ad4.z), m3 = lrelu(asd.w+ad4.w);
  for (int e = r0+lane; e < r1; e += 64){
    int s = csr[e];
    float4 a4 = as_[s];
    m0 = fmaxf(m0, lrelu(a4.x+ad4.x));
    m1 = fmaxf(m1, lrelu(a4.y+ad4.y));
    m2 = fmaxf(m2, lrelu(a4.z+ad4.z));
    m3 = fmaxf(m3, lrelu(a4.w+ad4.w));
  }
  #pragma unroll
  for (int mk=32; mk>=1; mk>>=1){
    m0 = fmaxf(m0, __shfl_xor(m0,mk));
    m1 = fmaxf(m1, __shfl_xor(m1,mk));
    m2 = fmaxf(m2, __shfl_xor(m2,mk));
    m3 = fmaxf(m3, __shfl_xor(m3,mk));
  }
  // pass 2: lane owns channels 2*lane, 2*lane+1 ; head = lane>>4
  int hh = lane >> 4;
  float mh  = (hh&2) ? ((hh&1)?m3:m2)       : ((hh&1)?m1:m0);
  float adh = (hh&2) ? ((hh&1)?ad4.w:ad4.z) : ((hh&1)?ad4.y:ad4.x);
  float asv = (hh&2) ? ((hh&1)?asd.w:asd.z) : ((hh&1)?asd.y:asd.x);
  float acc0, acc1, den;
  {
    float w = __expf(lrelu(asv+adh)-mh);
    float2 hv = *(const float2*)&hin[(size_t)d*128 + 2*lane];
    acc0 = w*hv.x; acc1 = w*hv.y; den = w;
  }
  int e = r0;
  for (; e+3 < r1; e += 4){
    int s0=csr[e], s1=csr[e+1], s2=csr[e+2], s3=csr[e+3];
    float4 a0=as_[s0], a1=as_[s1], a2=as_[s2], a3=as_[s3];
    float2 h0=*(const float2*)&hin[(size_t)s0*128+2*lane];
    float2 h1=*(const float2*)&hin[(size_t)s1*128+2*lane];
    float2 h2=*(const float2*)&hin[(size_t)s2*128+2*lane];
    float2 h3=*(const float2*)&hin[(size_t)s3*128+2*lane];
    float av0=(hh&2)?((hh&1)?a0.w:a0.z):((hh&1)?a0.y:a0.x);
    float av1=(hh&2)?((hh&1)?a1.w:a1.z):((hh&1)?a1.y:a1.x);
    float av2=(hh&2)?((hh&1)?a2.w:a2.z):((hh&1)?a2.y:a2.x);
    float av3=(hh&2)?((hh&1)?a3.w:a3.z):((hh&1)?a3.y:a3.x);
    float w0=__expf(lrelu(av0+adh)-mh);
    float w1=__expf(lrelu(av1+adh)-mh);
    float w2=__expf(lrelu(av2+adh)-mh);
    float w3=__expf(lrelu(av3+adh)-mh);
    acc0=fmaf(w0,h0.x,acc0); acc1=fmaf(w0,h0.y,acc1); den+=w0;
    acc0=fmaf(w1,h1.x,acc0); acc1=fmaf(w1,h1.y,acc1); den+=w1;
    acc0=fmaf(w2,h2.x,acc0); acc1=fmaf(w2,h2.y,acc1); den+=w2;
    acc0=fmaf(w3,h3.x,acc0); acc1=fmaf(w3,h3.y,acc1); den+=w3;
  }
  for (; e < r1; ++e){
    int s = csr[e];
    float4 a4 = as_[s];
    float av=(hh&2)?((hh&1)?a4.w:a4.z):((hh&1)?a4.y:a4.x);
    float w=__expf(lrelu(av+adh)-mh);
    float2 hv=*(const float2*)&hin[(size_t)s*128+2*lane];
    acc0=fmaf(w,hv.x,acc0); acc1=fmaf(w,hv.y,acc1); den+=w;
  }
  float inv = 1.0f/den;
  float2 bv = *(const float2*)&bias[2*lane];
  float o0 = fmaxf(fmaf(acc0,inv,bv.x), 0.f);
  float o1 = fmaxf(fmaf(acc1,inv,bv.y), 0.f);
  *(float2*)&hout[(size_t)d*128 + 2*lane] = make_float2(o0,o1);
}

// ---------------- aggregation layer 3 (1 head x 32 ch) + fused final linear ----------------
__global__ __launch_bounds__(256) void agg_h1_lin(const float* __restrict__ hin,
    const float* __restrict__ as_, const float* __restrict__ ad_,
    const int* __restrict__ offs, const int* __restrict__ csr,
    const float* __restrict__ b3, const float* __restrict__ Wlin, const float* __restrict__ blin,
    float* __restrict__ out, int n){
  int wid = (blockIdx.x*256 + threadIdx.x) >> 6;
  int lane = threadIdx.x & 63;
  if (wid >= n) return;
  const int d = wid;
  float add = ad_[d];
  float asd = as_[d];
  int r0 = offs[d], r1 = offs[d+1];
  float m = lrelu(asd+add);
  for (int e = r0+lane; e < r1; e += 64){
    int s = csr[e];
    m = fmaxf(m, lrelu(as_[s]+add));
  }
  #pragma unroll
  for (int mk=32; mk>=1; mk>>=1) m = fmaxf(m, __shfl_xor(m,mk));
  int c = lane & 31;
  float acc, den;
  {
    float w = __expf(lrelu(asd+add)-m);
    acc = w*hin[(size_t)d*32 + c]; den = w;
  }
  int e = r0;
  for (; e+3 < r1; e += 4){
    int s0=csr[e], s1=csr[e+1], s2=csr[e+2], s3=csr[e+3];
    float a0=as_[s0], a1=as_[s1], a2=as_[s2], a3=as_[s3];
    float v0=hin[(size_t)s0*32+c], v1=hin[(size_t)s1*32+c];
    float v2=hin[(size_t)s2*32+c], v3=hin[(size_t)s3*32+c];
    float w0=__expf(lrelu(a0+add)-m), w1=__expf(lrelu(a1+add)-m);
    float w2=__expf(lrelu(a2+add)-m), w3=__expf(lrelu(a3+add)-m);
    acc=fmaf(w0,v0,acc); den+=w0;
    acc=fmaf(w1,v1,acc); den+=w1;
    acc=fmaf(w2,v2,acc); den+=w2;
    acc=fmaf(w3,v3,acc); den+=w3;
  }
  for (; e < r1; ++e){
    int s = csr[e];
    float w=__expf(lrelu(as_[s]+add)-m);
    acc=fmaf(w,hin[(size_t)s*32+c],acc); den+=w;
  }
  float v = fmaxf(acc/den + b3[c], 0.f);
  float y0 = v*Wlin[c*2+0];
  float y1 = v*Wlin[c*2+1];
  #pragma unroll
  for (int mk=16; mk>=1; mk>>=1){ y0 += __shfl_xor(y0,mk); y1 += __shfl_xor(y1,mk); }
  if (lane==0){ out[(size_t)d*2+0] = y0 + blin[0]; out[(size_t)d*2+1] = y1 + blin[1]; }
}

extern "C" void kernel_launch(void* const* d_in, const int* in_sizes, int n_in,
                              void* d_out, int out_size, void* d_ws, size_t ws_size,
                              hipStream_t stream){
  const int N = in_sizes[0] / 128;     // 50000
  const int E = in_sizes[1] / 2;       // 1600000
  const float* x    = (const float*)d_in[0];
  const int*   ei   = (const int*)d_in[1];
  const int*   srcv = ei;
  const int*   dstv = ei + E;
  const float* W1 = (const float*)d_in[2];
  const float* a1s= (const float*)d_in[3];
  const float* a1d= (const float*)d_in[4];
  const float* b1 = (const float*)d_in[5];
  const float* W2 = (const float*)d_in[6];
  const float* a2s= (const float*)d_in[7];
  const float* a2d= (const float*)d_in[8];
  const float* b2 = (const float*)d_in[9];
  const float* W3 = (const float*)d_in[10];
  const float* a3s= (const float*)d_in[11];
  const float* a3d= (const float*)d_in[12];
  const float* b3 = (const float*)d_in[13];
  const float* Wlin=(const float*)d_in[14];
  const float* blin=(const float*)d_in[15];
  float* out = (float*)d_out;

  char* wp = (char*)d_ws;
  auto alloc = [&](size_t bytes)->void*{
    void* p = (void*)wp;
    wp += (bytes + 255) & ~(size_t)255;
    return p;
  };
  float* h_a   = (float*)alloc((size_t)N*128*4);
  float* h_b   = (float*)alloc((size_t)N*128*4);
  float* as_   = (float*)alloc((size_t)N*4*4);
  float* ad_   = (float*)alloc((size_t)N*4*4);
  int*   counts= (int*)alloc((size_t)N*4);
  int*   offs  = (int*)alloc((size_t)(N+1)*4);
  int*   cursor= (int*)alloc((size_t)N*4);
  int*   csr   = (int*)alloc((size_t)E*4);

  const int gridE = (E + 255)/256;
  const int gridW = (N + 3)/4;      // wave-per-node kernels

  // CSR build (dst unchanged across layers -> build once)
  hipMemsetAsync(counts, 0, (size_t)N*4, stream);
  hist_kernel<<<gridE, 256, 0, stream>>>(dstv, counts, E);
  scan_kernel<<<1, 256, 0, stream>>>(counts, offs, cursor, N);
  scatter_kernel<<<gridE, 256, 0, stream>>>(srcv, dstv, cursor, csr, E);

  // Layer 1
  gemm_k128<128,8><<<(N+63)/64, 256, 0, stream>>>(x, W1, h_a, N);
  alpha_h4<<<gridW, 256, 0, stream>>>(h_a, a1s, a1d, (float4*)as_, (float4*)ad_, N);
  agg_h4<<<gridW, 256, 0, stream>>>(h_a, (const float4*)as_, (const float4*)ad_, offs, csr, b1, h_b, N);

  // Layer 2
  gemm_k128<128,8><<<(N+63)/64, 256, 0, stream>>>(h_b, W2, h_a, N);
  alpha_h4<<<gridW, 256, 0, stream>>>(h_a, a2s, a2d, (float4*)as_, (float4*)ad_, N);
  agg_h4<<<gridW, 256, 0, stream>>>(h_a, (const float4*)as_, (const float4*)ad_, offs, csr, b2, h_b, N);

  // Layer 3 (32 out) + final linear fused into aggregation
  gemm_k128<32,4><<<(N+127)/128, 256, 0, stream>>>(h_b, W3, h_a, N);
  alpha_h1<<<gridW, 256, 0, stream>>>(h_a, a3s, a3d, as_, ad_, N);
  agg_h1_lin<<<gridW, 256, 0, stream>>>(h_a, as_, ad_, offs, csr, b3, Wlin, blin, out, N);
}

// Round 2
// 772.730 us; speedup vs baseline: 1.0618x; 1.0618x over previous
//
#include <hip/hip_runtime.h>

#define NEG 0.2f
__device__ __forceinline__ float lrelu(float x){ return fmaxf(x, NEG*x); }

// ---------------- CSR build ----------------
__global__ __launch_bounds__(256) void hist_kernel(const int* __restrict__ dstv, int* __restrict__ counts, int E){
  int i = blockIdx.x*256 + threadIdx.x;
  if (i < E) atomicAdd(&counts[dstv[i]], 1);
}

__global__ __launch_bounds__(256) void scan_kernel(const int* __restrict__ counts, int* __restrict__ offs,
                                                   int* __restrict__ cursor, int n){
  __shared__ int wsum[4];
  __shared__ int carry_s;
  int tid = threadIdx.x, lane = tid & 63, wv = tid >> 6;
  if (tid == 0) carry_s = 0;
  __syncthreads();
  const int CH = 2048;
  int nch = (n + CH - 1)/CH;
  for (int ch=0; ch<nch; ++ch){
    int base_i = ch*CH + tid*8;
    int v[8], pre[8];
    #pragma unroll
    for (int j=0;j<8;++j){ int i=base_i+j; v[j]=(i<n)?counts[i]:0; }
    int t=0;
    #pragma unroll
    for (int j=0;j<8;++j){ pre[j]=t; t+=v[j]; }
    int incl=t;
    #pragma unroll
    for (int m=1;m<64;m<<=1){ int u=__shfl_up(incl,m); if(lane>=m) incl+=u; }
    int wexcl = incl - t;
    if (lane==63) wsum[wv]=incl;
    __syncthreads();
    int wbase=0;
    for (int w2=0;w2<wv;++w2) wbase+=wsum[w2];
    int total = wsum[0]+wsum[1]+wsum[2]+wsum[3];
    int base = carry_s + wbase + wexcl;
    #pragma unroll
    for (int j=0;j<8;++j){ int i=base_i+j; if(i<n){ int val=base+pre[j]; offs[i]=val; cursor[i]=val; } }
    __syncthreads();
    if (tid==0) carry_s += total;
    __syncthreads();
  }
  if (tid==0) offs[n]=carry_s;
}

__global__ __launch_bounds__(256) void scatter_kernel(const int* __restrict__ srcv, const int* __restrict__ dstv,
                                                      int* __restrict__ cursor, int* __restrict__ csr, int E){
  int i = blockIdx.x*256 + threadIdx.x;
  if (i < E){ int d=dstv[i]; int p=atomicAdd(&cursor[d],1); csr[p]=srcv[i]; }
}

// ---------------- GEMM: Y[n,NOUT] = X[n,128] @ W[128,NOUT], 8x8 thread tile ----------------
template<int NOUT>
__global__ __launch_bounds__(256) void gemm8(const float* __restrict__ X, const float* __restrict__ W,
                                             float* __restrict__ Y, int n){
  constexpr int NC = NOUT / 8;      // col groups (threads per row-group)
  constexpr int RG = 256 / NC;      // row groups
  constexpr int BM = RG * 8;        // rows per block
  __shared__ float Wl[128 * NOUT];
  for (int i = threadIdx.x; i < 128*NOUT/4; i += 256)
    ((float4*)Wl)[i] = ((const float4*)W)[i];
  __syncthreads();
  int cg = threadIdx.x % NC;
  int rg = threadIdx.x / NC;
  int row0 = blockIdx.x * BM + rg * 8;
  float acc[8][8];
  #pragma unroll
  for (int r=0;r<8;++r)
    #pragma unroll
    for (int c=0;c<8;++c) acc[r][c]=0.f;
  for (int k4 = 0; k4 < 32; ++k4){
    float4 xv[8];
    #pragma unroll
    for (int r = 0; r < 8; ++r){
      int row = row0 + r;
      xv[r] = (row < n) ? ((const float4*)(X + (size_t)row*128))[k4] : make_float4(0.f,0.f,0.f,0.f);
    }
    #pragma unroll
    for (int kk = 0; kk < 4; ++kk){
      int k = k4*4 + kk;
      float wv[8];
      #pragma unroll
      for (int c = 0; c < 8; ++c) wv[c] = Wl[k*NOUT + cg*8 + c];
      #pragma unroll
      for (int r = 0; r < 8; ++r){
        float xr = (kk==0)?xv[r].x:(kk==1)?xv[r].y:(kk==2)?xv[r].z:xv[r].w;
        #pragma unroll
        for (int c = 0; c < 8; ++c) acc[r][c] = fmaf(xr, wv[c], acc[r][c]);
      }
    }
  }
  #pragma unroll
  for (int r = 0; r < 8; ++r){
    int row = row0 + r;
    if (row < n){
      *(float4*)&Y[(size_t)row*NOUT + cg*8 + 0] = make_float4(acc[r][0],acc[r][1],acc[r][2],acc[r][3]);
      *(float4*)&Y[(size_t)row*NOUT + cg*8 + 4] = make_float4(acc[r][4],acc[r][5],acc[r][6],acc[r][7]);
    }
  }
}

// ---------------- alpha: per-node dot(h, a_src/a_dst) ----------------
__global__ __launch_bounds__(256) void alpha_h4(const float* __restrict__ h, const float* __restrict__ a_s,
                                                const float* __restrict__ a_d, float4* __restrict__ as_,
                                                float4* __restrict__ ad_, int n){
  int wid = (blockIdx.x*256 + threadIdx.x) >> 6;
  int lane = threadIdx.x & 63;
  if (wid >= n) return;
  const float* row = h + (size_t)wid*128;
  float x0 = row[lane], x1 = row[lane+64];
  float s0 = x0*a_s[lane], s1 = x1*a_s[lane+64];
  float d0 = x0*a_d[lane], d1 = x1*a_d[lane+64];
  #pragma unroll
  for (int m=16;m>=1;m>>=1){
    s0 += __shfl_xor(s0,m); s1 += __shfl_xor(s1,m);
    d0 += __shfl_xor(d0,m); d1 += __shfl_xor(d1,m);
  }
  float h0s=__shfl(s0,0), h1s=__shfl(s0,32), h2s=__shfl(s1,0), h3s=__shfl(s1,32);
  float h0d=__shfl(d0,0), h1d=__shfl(d0,32), h2d=__shfl(d1,0), h3d=__shfl(d1,32);
  if (lane==0){ as_[wid]=make_float4(h0s,h1s,h2s,h3s); ad_[wid]=make_float4(h0d,h1d,h2d,h3d); }
}

__global__ __launch_bounds__(256) void alpha_h1(const float* __restrict__ h, const float* __restrict__ a_s,
                                                const float* __restrict__ a_d, float* __restrict__ as_,
                                                float* __restrict__ ad_, int n){
  int wid = (blockIdx.x*256 + threadIdx.x) >> 6;
  int lane = threadIdx.x & 63;
  if (wid >= n) return;
  float s=0.f, d=0.f;
  if (lane < 32){ float x = h[(size_t)wid*32 + lane]; s = x*a_s[lane]; d = x*a_d[lane]; }
  #pragma unroll
  for (int m=16;m>=1;m>>=1){ s += __shfl_xor(s,m); d += __shfl_xor(d,m); }
  if (lane==0){ as_[wid]=s; ad_[wid]=d; }
}

__device__ __forceinline__ float sel4(int hh, float4 v){
  return (hh&2) ? ((hh&1)?v.w:v.z) : ((hh&1)?v.y:v.x);
}

// ---------------- aggregation, 4 heads x 32 ch: half-wave per edge ----------------
__global__ __launch_bounds__(256) void agg_h4(const float* __restrict__ hin,
    const float4* __restrict__ as_, const float4* __restrict__ ad_,
    const int* __restrict__ offs, const int* __restrict__ csr,
    const float* __restrict__ bias, float* __restrict__ hout, int n){
  int wid = (blockIdx.x*256 + threadIdx.x) >> 6;
  int lane = threadIdx.x & 63;
  if (wid >= n) return;
  const int d = wid;
  float4 ad4 = ad_[d];
  float4 asd = as_[d];
  int r0 = offs[d], r1 = offs[d+1];
  // pass 1: per-head max (lane-parallel over edges), incl. self-loop
  float m0 = lrelu(asd.x+ad4.x), m1 = lrelu(asd.y+ad4.y);
  float m2 = lrelu(asd.z+ad4.z), m3 = lrelu(asd.w+ad4.w);
  for (int e = r0+lane; e < r1; e += 64){
    int s = csr[e];
    float4 a4 = as_[s];
    m0 = fmaxf(m0, lrelu(a4.x+ad4.x));
    m1 = fmaxf(m1, lrelu(a4.y+ad4.y));
    m2 = fmaxf(m2, lrelu(a4.z+ad4.z));
    m3 = fmaxf(m3, lrelu(a4.w+ad4.w));
  }
  #pragma unroll
  for (int mk=32; mk>=1; mk>>=1){
    m0 = fmaxf(m0, __shfl_xor(m0,mk));
    m1 = fmaxf(m1, __shfl_xor(m1,mk));
    m2 = fmaxf(m2, __shfl_xor(m2,mk));
    m3 = fmaxf(m3, __shfl_xor(m3,mk));
  }
  // pass 2: half-wave per edge; lane owns channels 4*cl..4*cl+3 of its half's edge
  int half = lane >> 5;
  int cl = lane & 31;        // channel group 0..31 -> 4 channels
  int hh = cl >> 3;          // head
  float mh  = (hh&2) ? ((hh&1)?m3:m2)       : ((hh&1)?m1:m0);
  float adh = (hh&2) ? ((hh&1)?ad4.w:ad4.z) : ((hh&1)?ad4.y:ad4.x);
  float asv = (hh&2) ? ((hh&1)?asd.w:asd.z) : ((hh&1)?asd.y:asd.x);
  float acc0=0.f, acc1=0.f, acc2=0.f, acc3=0.f, den=0.f;
  if (half == 0){
    float w = __expf(lrelu(asv+adh)-mh);
    float4 hv = *(const float4*)&hin[(size_t)d*128 + 4*cl];
    acc0 = w*hv.x; acc1 = w*hv.y; acc2 = w*hv.z; acc3 = w*hv.w; den = w;
  }
  int e = r0 + half;
  for (; e+6 < r1; e += 8){
    int s0=csr[e], s1=csr[e+2], s2=csr[e+4], s3=csr[e+6];
    float4 a0=as_[s0], a1=as_[s1], a2=as_[s2], a3=as_[s3];
    float4 h0=*(const float4*)&hin[(size_t)s0*128+4*cl];
    float4 h1=*(const float4*)&hin[(size_t)s1*128+4*cl];
    float4 h2=*(const float4*)&hin[(size_t)s2*128+4*cl];
    float4 h3=*(const float4*)&hin[(size_t)s3*128+4*cl];
    float w0=__expf(lrelu(sel4(hh,a0)+adh)-mh);
    float w1=__expf(lrelu(sel4(hh,a1)+adh)-mh);
    float w2=__expf(lrelu(sel4(hh,a2)+adh)-mh);
    float w3=__expf(lrelu(sel4(hh,a3)+adh)-mh);
    acc0=fmaf(w0,h0.x,acc0); acc1=fmaf(w0,h0.y,acc1); acc2=fmaf(w0,h0.z,acc2); acc3=fmaf(w0,h0.w,acc3); den+=w0;
    acc0=fmaf(w1,h1.x,acc0); acc1=fmaf(w1,h1.y,acc1); acc2=fmaf(w1,h1.z,acc2); acc3=fmaf(w1,h1.w,acc3); den+=w1;
    acc0=fmaf(w2,h2.x,acc0); acc1=fmaf(w2,h2.y,acc1); acc2=fmaf(w2,h2.z,acc2); acc3=fmaf(w2,h2.w,acc3); den+=w2;
    acc0=fmaf(w3,h3.x,acc0); acc1=fmaf(w3,h3.y,acc1); acc2=fmaf(w3,h3.z,acc2); acc3=fmaf(w3,h3.w,acc3); den+=w3;
  }
  for (; e < r1; e += 2){
    int s = csr[e];
    float4 a4 = as_[s];
    float w = __expf(lrelu(sel4(hh,a4)+adh)-mh);
    float4 hv = *(const float4*)&hin[(size_t)s*128+4*cl];
    acc0=fmaf(w,hv.x,acc0); acc1=fmaf(w,hv.y,acc1); acc2=fmaf(w,hv.z,acc2); acc3=fmaf(w,hv.w,acc3); den+=w;
  }
  // combine halves
  acc0 += __shfl_xor(acc0,32); acc1 += __shfl_xor(acc1,32);
  acc2 += __shfl_xor(acc2,32); acc3 += __shfl_xor(acc3,32);
  den  += __shfl_xor(den,32);
  if (half == 0){
    float inv = 1.0f/den;
    float4 bv = *(const float4*)&bias[4*cl];
    float4 o;
    o.x = fmaxf(fmaf(acc0,inv,bv.x), 0.f);
    o.y = fmaxf(fmaf(acc1,inv,bv.y), 0.f);
    o.z = fmaxf(fmaf(acc2,inv,bv.z), 0.f);
    o.w = fmaxf(fmaf(acc3,inv,bv.w), 0.f);
    *(float4*)&hout[(size_t)d*128 + 4*cl] = o;
  }
}

// ---------------- aggregation layer 3 (1 head x 32 ch) + fused final linear ----------------
__global__ __launch_bounds__(256) void agg_h1_lin(const float* __restrict__ hin,
    const float* __restrict__ as_, const float* __restrict__ ad_,
    const int* __restrict__ offs, const int* __restrict__ csr,
    const float* __restrict__ b3, const float* __restrict__ Wlin, const float* __restrict__ blin,
    float* __restrict__ out, int n){
  int wid = (blockIdx.x*256 + threadIdx.x) >> 6;
  int lane = threadIdx.x & 63;
  if (wid >= n) return;
  const int d = wid;
  float add = ad_[d];
  float asd = as_[d];
  int r0 = offs[d], r1 = offs[d+1];
  float m = lrelu(asd+add);
  for (int e = r0+lane; e < r1; e += 64){
    int s = csr[e];
    m = fmaxf(m, lrelu(as_[s]+add));
  }
  #pragma unroll
  for (int mk=32; mk>=1; mk>>=1) m = fmaxf(m, __shfl_xor(m,mk));
  int half = lane >> 5;
  int c = lane & 31;
  float acc=0.f, den=0.f;
  if (half == 0){
    float w = __expf(lrelu(asd+add)-m);
    acc = w*hin[(size_t)d*32 + c]; den = w;
  }
  int e = r0 + half;
  for (; e+6 < r1; e += 8){
    int s0=csr[e], s1=csr[e+2], s2=csr[e+4], s3=csr[e+6];
    float a0=as_[s0], a1=as_[s1], a2=as_[s2], a3=as_[s3];
    float v0=hin[(size_t)s0*32+c], v1=hin[(size_t)s1*32+c];
    float v2=hin[(size_t)s2*32+c], v3=hin[(size_t)s3*32+c];
    float w0=__expf(lrelu(a0+add)-m), w1=__expf(lrelu(a1+add)-m);
    float w2=__expf(lrelu(a2+add)-m), w3=__expf(lrelu(a3+add)-m);
    acc=fmaf(w0,v0,acc); den+=w0;
    acc=fmaf(w1,v1,acc); den+=w1;
    acc=fmaf(w2,v2,acc); den+=w2;
    acc=fmaf(w3,v3,acc); den+=w3;
  }
  for (; e < r1; e += 2){
    int s = csr[e];
    float w=__expf(lrelu(as_[s]+add)-m);
    acc=fmaf(w,hin[(size_t)s*32+c],acc); den+=w;
  }
  acc += __shfl_xor(acc,32);
  den += __shfl_xor(den,32);
  float v = fmaxf(acc/den + b3[c], 0.f);
  float y0 = v*Wlin[c*2+0];
  float y1 = v*Wlin[c*2+1];
  #pragma unroll
  for (int mk=16; mk>=1; mk>>=1){ y0 += __shfl_xor(y0,mk); y1 += __shfl_xor(y1,mk); }
  if (lane==0){ out[(size_t)d*2+0] = y0 + blin[0]; out[(size_t)d*2+1] = y1 + blin[1]; }
}

extern "C" void kernel_launch(void* const* d_in, const int* in_sizes, int n_in,
                              void* d_out, int out_size, void* d_ws, size_t ws_size,
                              hipStream_t stream){
  const int N = in_sizes[0] / 128;     // 50000
  const int E = in_sizes[1] / 2;       // 1600000
  const float* x    = (const float*)d_in[0];
  const int*   ei   = (const int*)d_in[1];
  const int*   srcv = ei;
  const int*   dstv = ei + E;
  const float* W1 = (const float*)d_in[2];
  const float* a1s= (const float*)d_in[3];
  const float* a1d= (const float*)d_in[4];
  const float* b1 = (const float*)d_in[5];
  const float* W2 = (const float*)d_in[6];
  const float* a2s= (const float*)d_in[7];
  const float* a2d= (const float*)d_in[8];
  const float* b2 = (const float*)d_in[9];
  const float* W3 = (const float*)d_in[10];
  const float* a3s= (const float*)d_in[11];
  const float* a3d= (const float*)d_in[12];
  const float* b3 = (const float*)d_in[13];
  const float* Wlin=(const float*)d_in[14];
  const float* blin=(const float*)d_in[15];
  float* out = (float*)d_out;

  char* wp = (char*)d_ws;
  auto alloc = [&](size_t bytes)->void*{
    void* p = (void*)wp;
    wp += (bytes + 255) & ~(size_t)255;
    return p;
  };
  float* h_a   = (float*)alloc((size_t)N*128*4);
  float* h_b   = (float*)alloc((size_t)N*128*4);
  float* as_   = (float*)alloc((size_t)N*4*4);
  float* ad_   = (float*)alloc((size_t)N*4*4);
  int*   counts= (int*)alloc((size_t)N*4);
  int*   offs  = (int*)alloc((size_t)(N+1)*4);
  int*   cursor= (int*)alloc((size_t)N*4);
  int*   csr   = (int*)alloc((size_t)E*4);

  const int gridE = (E + 255)/256;
  const int gridW = (N + 3)/4;      // wave-per-node kernels

  // CSR build (dst unchanged across layers -> build once)
  hipMemsetAsync(counts, 0, (size_t)N*4, stream);
  hist_kernel<<<gridE, 256, 0, stream>>>(dstv, counts, E);
  scan_kernel<<<1, 256, 0, stream>>>(counts, offs, cursor, N);
  scatter_kernel<<<gridE, 256, 0, stream>>>(srcv, dstv, cursor, csr, E);

  // Layer 1
  gemm8<128><<<(N+127)/128, 256, 0, stream>>>(x, W1, h_a, N);
  alpha_h4<<<gridW, 256, 0, stream>>>(h_a, a1s, a1d, (float4*)as_, (float4*)ad_, N);
  agg_h4<<<gridW, 256, 0, stream>>>(h_a, (const float4*)as_, (const float4*)ad_, offs, csr, b1, h_b, N);

  // Layer 2
  gemm8<128><<<(N+127)/128, 256, 0, stream>>>(h_b, W2, h_a, N);
  alpha_h4<<<gridW, 256, 0, stream>>>(h_a, a2s, a2d, (float4*)as_, (float4*)ad_, N);
  agg_h4<<<gridW, 256, 0, stream>>>(h_a, (const float4*)as_, (const float4*)ad_, offs, csr, b2, h_b, N);

  // Layer 3 (32 out) + final linear fused into aggregation
  gemm8<32><<<(N+511)/512, 256, 0, stream>>>(h_b, W3, h_a, N);
  alpha_h1<<<gridW, 256, 0, stream>>>(h_a, a3s, a3d, as_, ad_, N);
  agg_h1_lin<<<gridW, 256, 0, stream>>>(h_a, as_, ad_, offs, csr, b3, Wlin, blin, out, N);
}

// Round 3
// 752.903 us; speedup vs baseline: 1.0898x; 1.0263x over previous
//
#include <hip/hip_runtime.h>

#define NEG 0.2f
__device__ __forceinline__ float lrelu(float x){ return fmaxf(x, NEG*x); }

__device__ __forceinline__ float bf2f(unsigned short u){
  union{unsigned int i; float f;} v; v.i = ((unsigned int)u)<<16; return v.f;
}
__device__ __forceinline__ unsigned short f2bf(float f){
  union{float f; unsigned int i;} v; v.f = f;
  unsigned int b = v.i;
  b += 0x7FFFu + ((b>>16)&1u);   // round-to-nearest-even
  return (unsigned short)(b>>16);
}

// ---------------- CSR build ----------------
__global__ __launch_bounds__(256) void hist_kernel(const int* __restrict__ dstv, int* __restrict__ counts, int E){
  int i = blockIdx.x*256 + threadIdx.x;
  if (i < E) atomicAdd(&counts[dstv[i]], 1);
}

__global__ __launch_bounds__(256) void scan_kernel(const int* __restrict__ counts, int* __restrict__ offs,
                                                   int* __restrict__ cursor, int n){
  __shared__ int wsum[4];
  __shared__ int carry_s;
  int tid = threadIdx.x, lane = tid & 63, wv = tid >> 6;
  if (tid == 0) carry_s = 0;
  __syncthreads();
  const int CH = 2048;
  int nch = (n + CH - 1)/CH;
  for (int ch=0; ch<nch; ++ch){
    int base_i = ch*CH + tid*8;
    int v[8], pre[8];
    #pragma unroll
    for (int j=0;j<8;++j){ int i=base_i+j; v[j]=(i<n)?counts[i]:0; }
    int t=0;
    #pragma unroll
    for (int j=0;j<8;++j){ pre[j]=t; t+=v[j]; }
    int incl=t;
    #pragma unroll
    for (int m=1;m<64;m<<=1){ int u=__shfl_up(incl,m); if(lane>=m) incl+=u; }
    int wexcl = incl - t;
    if (lane==63) wsum[wv]=incl;
    __syncthreads();
    int wbase=0;
    for (int w2=0;w2<wv;++w2) wbase+=wsum[w2];
    int total = wsum[0]+wsum[1]+wsum[2]+wsum[3];
    int base = carry_s + wbase + wexcl;
    #pragma unroll
    for (int j=0;j<8;++j){ int i=base_i+j; if(i<n){ int val=base+pre[j]; offs[i]=val; cursor[i]=val; } }
    __syncthreads();
    if (tid==0) carry_s += total;
    __syncthreads();
  }
  if (tid==0) offs[n]=carry_s;
}

__global__ __launch_bounds__(256) void scatter_kernel(const int* __restrict__ srcv, const int* __restrict__ dstv,
                                                      int* __restrict__ cursor, int* __restrict__ csr, int E){
  int i = blockIdx.x*256 + threadIdx.x;
  if (i < E){ int d=dstv[i]; int p=atomicAdd(&cursor[d],1); csr[p]=srcv[i]; }
}

// ---------------- GEMM: Y[n,NOUT] = X[n,128] @ W[128,NOUT], 8x8 thread tile ----------------
template<int NOUT>
__global__ __launch_bounds__(256) void gemm8(const float* __restrict__ X, const float* __restrict__ W,
                                             float* __restrict__ Y, int n){
  constexpr int NC = NOUT / 8;      // col groups (threads per row-group)
  constexpr int RG = 256 / NC;      // row groups
  constexpr int BM = RG * 8;        // rows per block
  __shared__ float Wl[128 * NOUT];
  for (int i = threadIdx.x; i < 128*NOUT/4; i += 256)
    ((float4*)Wl)[i] = ((const float4*)W)[i];
  __syncthreads();
  int cg = threadIdx.x % NC;
  int rg = threadIdx.x / NC;
  int row0 = blockIdx.x * BM + rg * 8;
  float acc[8][8];
  #pragma unroll
  for (int r=0;r<8;++r)
    #pragma unroll
    for (int c=0;c<8;++c) acc[r][c]=0.f;
  for (int k4 = 0; k4 < 32; ++k4){
    float4 xv[8];
    #pragma unroll
    for (int r = 0; r < 8; ++r){
      int row = row0 + r;
      xv[r] = (row < n) ? ((const float4*)(X + (size_t)row*128))[k4] : make_float4(0.f,0.f,0.f,0.f);
    }
    #pragma unroll
    for (int kk = 0; kk < 4; ++kk){
      int k = k4*4 + kk;
      float wv[8];
      #pragma unroll
      for (int c = 0; c < 8; ++c) wv[c] = Wl[k*NOUT + cg*8 + c];
      #pragma unroll
      for (int r = 0; r < 8; ++r){
        float xr = (kk==0)?xv[r].x:(kk==1)?xv[r].y:(kk==2)?xv[r].z:xv[r].w;
        #pragma unroll
        for (int c = 0; c < 8; ++c) acc[r][c] = fmaf(xr, wv[c], acc[r][c]);
      }
    }
  }
  #pragma unroll
  for (int r = 0; r < 8; ++r){
    int row = row0 + r;
    if (row < n){
      *(float4*)&Y[(size_t)row*NOUT + cg*8 + 0] = make_float4(acc[r][0],acc[r][1],acc[r][2],acc[r][3]);
      *(float4*)&Y[(size_t)row*NOUT + cg*8 + 4] = make_float4(acc[r][4],acc[r][5],acc[r][6],acc[r][7]);
    }
  }
}

// ---------------- alpha: per-node dot(h, a_src/a_dst) + bf16 message table ----------------
__global__ __launch_bounds__(256) void alpha_h4(const float* __restrict__ h, const float* __restrict__ a_s,
                                                const float* __restrict__ a_d, float4* __restrict__ as_,
                                                float4* __restrict__ ad_, unsigned short* __restrict__ hb, int n){
  int wid = (blockIdx.x*256 + threadIdx.x) >> 6;
  int lane = threadIdx.x & 63;
  if (wid >= n) return;
  const float* row = h + (size_t)wid*128;
  float x0 = row[lane], x1 = row[lane+64];
  unsigned short* hbrow = hb + (size_t)wid*128;
  hbrow[lane]    = f2bf(x0);
  hbrow[lane+64] = f2bf(x1);
  float s0 = x0*a_s[lane], s1 = x1*a_s[lane+64];
  float d0 = x0*a_d[lane], d1 = x1*a_d[lane+64];
  #pragma unroll
  for (int m=16;m>=1;m>>=1){
    s0 += __shfl_xor(s0,m); s1 += __shfl_xor(s1,m);
    d0 += __shfl_xor(d0,m); d1 += __shfl_xor(d1,m);
  }
  float h0s=__shfl(s0,0), h1s=__shfl(s0,32), h2s=__shfl(s1,0), h3s=__shfl(s1,32);
  float h0d=__shfl(d0,0), h1d=__shfl(d0,32), h2d=__shfl(d1,0), h3d=__shfl(d1,32);
  if (lane==0){ as_[wid]=make_float4(h0s,h1s,h2s,h3s); ad_[wid]=make_float4(h0d,h1d,h2d,h3d); }
}

__global__ __launch_bounds__(256) void alpha_h1(const float* __restrict__ h, const float* __restrict__ a_s,
                                                const float* __restrict__ a_d, float* __restrict__ as_,
                                                float* __restrict__ ad_, unsigned short* __restrict__ hb, int n){
  int wid = (blockIdx.x*256 + threadIdx.x) >> 6;
  int lane = threadIdx.x & 63;
  if (wid >= n) return;
  float s=0.f, d=0.f;
  if (lane < 32){
    float x = h[(size_t)wid*32 + lane];
    hb[(size_t)wid*32 + lane] = f2bf(x);
    s = x*a_s[lane]; d = x*a_d[lane];
  }
  #pragma unroll
  for (int m=16;m>=1;m>>=1){ s += __shfl_xor(s,m); d += __shfl_xor(d,m); }
  if (lane==0){ as_[wid]=s; ad_[wid]=d; }
}

__device__ __forceinline__ float sel4(int hh, float4 v){
  return (hh&2) ? ((hh&1)?v.w:v.z) : ((hh&1)?v.y:v.x);
}

// ---------------- aggregation, 4 heads x 32 ch: half-wave per edge, bf16 messages ----------------
__global__ __launch_bounds__(256) void agg_h4(const unsigned short* __restrict__ hb,
    const float4* __restrict__ as_, const float4* __restrict__ ad_,
    const int* __restrict__ offs, const int* __restrict__ csr,
    const float* __restrict__ bias, float* __restrict__ hout, int n){
  int wid = (blockIdx.x*256 + threadIdx.x) >> 6;
  int lane = threadIdx.x & 63;
  if (wid >= n) return;
  const int d = wid;
  float4 ad4 = ad_[d];
  float4 asd = as_[d];
  int r0 = offs[d], r1 = offs[d+1];
  // pass 1: per-head max (lane-parallel over edges), incl. self-loop
  float m0 = lrelu(asd.x+ad4.x), m1 = lrelu(asd.y+ad4.y);
  float m2 = lrelu(asd.z+ad4.z), m3 = lrelu(asd.w+ad4.w);
  for (int e = r0+lane; e < r1; e += 64){
    int s = csr[e];
    float4 a4 = as_[s];
    m0 = fmaxf(m0, lrelu(a4.x+ad4.x));
    m1 = fmaxf(m1, lrelu(a4.y+ad4.y));
    m2 = fmaxf(m2, lrelu(a4.z+ad4.z));
    m3 = fmaxf(m3, lrelu(a4.w+ad4.w));
  }
  #pragma unroll
  for (int mk=32; mk>=1; mk>>=1){
    m0 = fmaxf(m0, __shfl_xor(m0,mk));
    m1 = fmaxf(m1, __shfl_xor(m1,mk));
    m2 = fmaxf(m2, __shfl_xor(m2,mk));
    m3 = fmaxf(m3, __shfl_xor(m3,mk));
  }
  // pass 2: half-wave per edge; lane owns channels 4*cl..4*cl+3 of its half's edge
  int half = lane >> 5;
  int cl = lane & 31;        // channel group -> 4 channels
  int hh = cl >> 3;          // head
  float mh  = (hh&2) ? ((hh&1)?m3:m2)       : ((hh&1)?m1:m0);
  float adh = (hh&2) ? ((hh&1)?ad4.w:ad4.z) : ((hh&1)?ad4.y:ad4.x);
  float asv = (hh&2) ? ((hh&1)?asd.w:asd.z) : ((hh&1)?asd.y:asd.x);
  float acc0=0.f, acc1=0.f, acc2=0.f, acc3=0.f, den=0.f;
  if (half == 0){
    float w = __expf(lrelu(asv+adh)-mh);
    ushort4 hv = *(const ushort4*)&hb[(size_t)d*128 + 4*cl];
    acc0 = w*bf2f(hv.x); acc1 = w*bf2f(hv.y); acc2 = w*bf2f(hv.z); acc3 = w*bf2f(hv.w); den = w;
  }
  int e = r0 + half;
  for (; e+14 < r1; e += 16){
    int s0=csr[e],   s1=csr[e+2],  s2=csr[e+4],  s3=csr[e+6];
    int s4=csr[e+8], s5=csr[e+10], s6=csr[e+12], s7=csr[e+14];
    float4 a0=as_[s0], a1=as_[s1], a2=as_[s2], a3=as_[s3];
    float4 a4=as_[s4], a5=as_[s5], a6=as_[s6], a7=as_[s7];
    ushort4 h0=*(const ushort4*)&hb[(size_t)s0*128+4*cl];
    ushort4 h1=*(const ushort4*)&hb[(size_t)s1*128+4*cl];
    ushort4 h2=*(const ushort4*)&hb[(size_t)s2*128+4*cl];
    ushort4 h3=*(const ushort4*)&hb[(size_t)s3*128+4*cl];
    ushort4 h4=*(const ushort4*)&hb[(size_t)s4*128+4*cl];
    ushort4 h5=*(const ushort4*)&hb[(size_t)s5*128+4*cl];
    ushort4 h6=*(const ushort4*)&hb[(size_t)s6*128+4*cl];
    ushort4 h7=*(const ushort4*)&hb[(size_t)s7*128+4*cl];
    float w0=__expf(lrelu(sel4(hh,a0)+adh)-mh);
    float w1=__expf(lrelu(sel4(hh,a1)+adh)-mh);
    float w2=__expf(lrelu(sel4(hh,a2)+adh)-mh);
    float w3=__expf(lrelu(sel4(hh,a3)+adh)-mh);
    float w4=__expf(lrelu(sel4(hh,a4)+adh)-mh);
    float w5=__expf(lrelu(sel4(hh,a5)+adh)-mh);
    float w6=__expf(lrelu(sel4(hh,a6)+adh)-mh);
    float w7=__expf(lrelu(sel4(hh,a7)+adh)-mh);
    acc0=fmaf(w0,bf2f(h0.x),acc0); acc1=fmaf(w0,bf2f(h0.y),acc1); acc2=fmaf(w0,bf2f(h0.z),acc2); acc3=fmaf(w0,bf2f(h0.w),acc3); den+=w0;
    acc0=fmaf(w1,bf2f(h1.x),acc0); acc1=fmaf(w1,bf2f(h1.y),acc1); acc2=fmaf(w1,bf2f(h1.z),acc2); acc3=fmaf(w1,bf2f(h1.w),acc3); den+=w1;
    acc0=fmaf(w2,bf2f(h2.x),acc0); acc1=fmaf(w2,bf2f(h2.y),acc1); acc2=fmaf(w2,bf2f(h2.z),acc2); acc3=fmaf(w2,bf2f(h2.w),acc3); den+=w2;
    acc0=fmaf(w3,bf2f(h3.x),acc0); acc1=fmaf(w3,bf2f(h3.y),acc1); acc2=fmaf(w3,bf2f(h3.z),acc2); acc3=fmaf(w3,bf2f(h3.w),acc3); den+=w3;
    acc0=fmaf(w4,bf2f(h4.x),acc0); acc1=fmaf(w4,bf2f(h4.y),acc1); acc2=fmaf(w4,bf2f(h4.z),acc2); acc3=fmaf(w4,bf2f(h4.w),acc3); den+=w4;
    acc0=fmaf(w5,bf2f(h5.x),acc0); acc1=fmaf(w5,bf2f(h5.y),acc1); acc2=fmaf(w5,bf2f(h5.z),acc2); acc3=fmaf(w5,bf2f(h5.w),acc3); den+=w5;
    acc0=fmaf(w6,bf2f(h6.x),acc0); acc1=fmaf(w6,bf2f(h6.y),acc1); acc2=fmaf(w6,bf2f(h6.z),acc2); acc3=fmaf(w6,bf2f(h6.w),acc3); den+=w6;
    acc0=fmaf(w7,bf2f(h7.x),acc0); acc1=fmaf(w7,bf2f(h7.y),acc1); acc2=fmaf(w7,bf2f(h7.z),acc2); acc3=fmaf(w7,bf2f(h7.w),acc3); den+=w7;
  }
  for (; e < r1; e += 2){
    int s = csr[e];
    float4 a4 = as_[s];
    float w = __expf(lrelu(sel4(hh,a4)+adh)-mh);
    ushort4 hv = *(const ushort4*)&hb[(size_t)s*128+4*cl];
    acc0=fmaf(w,bf2f(hv.x),acc0); acc1=fmaf(w,bf2f(hv.y),acc1); acc2=fmaf(w,bf2f(hv.z),acc2); acc3=fmaf(w,bf2f(hv.w),acc3); den+=w;
  }
  // combine halves
  acc0 += __shfl_xor(acc0,32); acc1 += __shfl_xor(acc1,32);
  acc2 += __shfl_xor(acc2,32); acc3 += __shfl_xor(acc3,32);
  den  += __shfl_xor(den,32);
  if (half == 0){
    float inv = 1.0f/den;
    float4 bv = *(const float4*)&bias[4*cl];
    float4 o;
    o.x = fmaxf(fmaf(acc0,inv,bv.x), 0.f);
    o.y = fmaxf(fmaf(acc1,inv,bv.y), 0.f);
    o.z = fmaxf(fmaf(acc2,inv,bv.z), 0.f);
    o.w = fmaxf(fmaf(acc3,inv,bv.w), 0.f);
    *(float4*)&hout[(size_t)d*128 + 4*cl] = o;
  }
}

// ---------------- aggregation layer 3 (1 head x 32 ch) + fused final linear ----------------
__global__ __launch_bounds__(256) void agg_h1_lin(const unsigned short* __restrict__ hb,
    const float* __restrict__ as_, const float* __restrict__ ad_,
    const int* __restrict__ offs, const int* __restrict__ csr,
    const float* __restrict__ b3, const float* __restrict__ Wlin, const float* __restrict__ blin,
    float* __restrict__ out, int n){
  int wid = (blockIdx.x*256 + threadIdx.x) >> 6;
  int lane = threadIdx.x & 63;
  if (wid >= n) return;
  const int d = wid;
  float add = ad_[d];
  float asd = as_[d];
  int r0 = offs[d], r1 = offs[d+1];
  float m = lrelu(asd+add);
  for (int e = r0+lane; e < r1; e += 64){
    int s = csr[e];
    m = fmaxf(m, lrelu(as_[s]+add));
  }
  #pragma unroll
  for (int mk=32; mk>=1; mk>>=1) m = fmaxf(m, __shfl_xor(m,mk));
  int half = lane >> 5;
  int c = lane & 31;
  float acc=0.f, den=0.f;
  if (half == 0){
    float w = __expf(lrelu(asd+add)-m);
    acc = w*bf2f(hb[(size_t)d*32 + c]); den = w;
  }
  int e = r0 + half;
  for (; e+14 < r1; e += 16){
    int s0=csr[e],   s1=csr[e+2],  s2=csr[e+4],  s3=csr[e+6];
    int s4=csr[e+8], s5=csr[e+10], s6=csr[e+12], s7=csr[e+14];
    float a0=as_[s0], a1=as_[s1], a2=as_[s2], a3=as_[s3];
    float a4=as_[s4], a5=as_[s5], a6=as_[s6], a7=as_[s7];
    float v0=bf2f(hb[(size_t)s0*32+c]), v1=bf2f(hb[(size_t)s1*32+c]);
    float v2=bf2f(hb[(size_t)s2*32+c]), v3=bf2f(hb[(size_t)s3*32+c]);
    float v4=bf2f(hb[(size_t)s4*32+c]), v5=bf2f(hb[(size_t)s5*32+c]);
    float v6=bf2f(hb[(size_t)s6*32+c]), v7=bf2f(hb[(size_t)s7*32+c]);
    float w0=__expf(lrelu(a0+add)-m), w1=__expf(lrelu(a1+add)-m);
    float w2=__expf(lrelu(a2+add)-m), w3=__expf(lrelu(a3+add)-m);
    float w4=__expf(lrelu(a4+add)-m), w5=__expf(lrelu(a5+add)-m);
    float w6=__expf(lrelu(a6+add)-m), w7=__expf(lrelu(a7+add)-m);
    acc=fmaf(w0,v0,acc); den+=w0;
    acc=fmaf(w1,v1,acc); den+=w1;
    acc=fmaf(w2,v2,acc); den+=w2;
    acc=fmaf(w3,v3,acc); den+=w3;
    acc=fmaf(w4,v4,acc); den+=w4;
    acc=fmaf(w5,v5,acc); den+=w5;
    acc=fmaf(w6,v6,acc); den+=w6;
    acc=fmaf(w7,v7,acc); den+=w7;
  }
  for (; e < r1; e += 2){
    int s = csr[e];
    float w=__expf(lrelu(as_[s]+add)-m);
    acc=fmaf(w,bf2f(hb[(size_t)s*32+c]),acc); den+=w;
  }
  acc += __shfl_xor(acc,32);
  den += __shfl_xor(den,32);
  float v = fmaxf(acc/den + b3[c], 0.f);
  float y0 = v*Wlin[c*2+0];
  float y1 = v*Wlin[c*2+1];
  #pragma unroll
  for (int mk=16; mk>=1; mk>>=1){ y0 += __shfl_xor(y0,mk); y1 += __shfl_xor(y1,mk); }
  if (lane==0){ out[(size_t)d*2+0] = y0 + blin[0]; out[(size_t)d*2+1] = y1 + blin[1]; }
}

extern "C" void kernel_launch(void* const* d_in, const int* in_sizes, int n_in,
                              void* d_out, int out_size, void* d_ws, size_t ws_size,
                              hipStream_t stream){
  const int N = in_sizes[0] / 128;     // 50000
  const int E = in_sizes[1] / 2;       // 1600000
  const float* x    = (const float*)d_in[0];
  const int*   ei   = (const int*)d_in[1];
  const int*   srcv = ei;
  const int*   dstv = ei + E;
  const float* W1 = (const float*)d_in[2];
  const float* a1s= (const float*)d_in[3];
  const float* a1d= (const float*)d_in[4];
  const float* b1 = (const float*)d_in[5];
  const float* W2 = (const float*)d_in[6];
  const float* a2s= (const float*)d_in[7];
  const float* a2d= (const float*)d_in[8];
  const float* b2 = (const float*)d_in[9];
  const float* W3 = (const float*)d_in[10];
  const float* a3s= (const float*)d_in[11];
  const float* a3d= (const float*)d_in[12];
  const float* b3 = (const float*)d_in[13];
  const float* Wlin=(const float*)d_in[14];
  const float* blin=(const float*)d_in[15];
  float* out = (float*)d_out;

  char* wp = (char*)d_ws;
  auto alloc = [&](size_t bytes)->void*{
    void* p = (void*)wp;
    wp += (bytes + 255) & ~(size_t)255;
    return p;
  };
  float* h_a   = (float*)alloc((size_t)N*128*4);
  float* h_b   = (float*)alloc((size_t)N*128*4);
  unsigned short* hb = (unsigned short*)alloc((size_t)N*128*2);
  float* as_   = (float*)alloc((size_t)N*4*4);
  float* ad_   = (float*)alloc((size_t)N*4*4);
  int*   counts= (int*)alloc((size_t)N*4);
  int*   offs  = (int*)alloc((size_t)(N+1)*4);
  int*   cursor= (int*)alloc((size_t)N*4);
  int*   csr   = (int*)alloc((size_t)E*4);

  const int gridE = (E + 255)/256;
  const int gridW = (N + 3)/4;      // wave-per-node kernels

  // CSR build (dst unchanged across layers -> build once)
  hipMemsetAsync(counts, 0, (size_t)N*4, stream);
  hist_kernel<<<gridE, 256, 0, stream>>>(dstv, counts, E);
  scan_kernel<<<1, 256, 0, stream>>>(counts, offs, cursor, N);
  scatter_kernel<<<gridE, 256, 0, stream>>>(srcv, dstv, cursor, csr, E);

  // Layer 1
  gemm8<128><<<(N+127)/128, 256, 0, stream>>>(x, W1, h_a, N);
  alpha_h4<<<gridW, 256, 0, stream>>>(h_a, a1s, a1d, (float4*)as_, (float4*)ad_, hb, N);
  agg_h4<<<gridW, 256, 0, stream>>>(hb, (const float4*)as_, (const float4*)ad_, offs, csr, b1, h_b, N);

  // Layer 2
  gemm8<128><<<(N+127)/128, 256, 0, stream>>>(h_b, W2, h_a, N);
  alpha_h4<<<gridW, 256, 0, stream>>>(h_a, a2s, a2d, (float4*)as_, (float4*)ad_, hb, N);
  agg_h4<<<gridW, 256, 0, stream>>>(hb, (const float4*)as_, (const float4*)ad_, offs, csr, b2, h_b, N);

  // Layer 3 (32 out) + final linear fused into aggregation
  gemm8<32><<<(N+511)/512, 256, 0, stream>>>(h_b, W3, h_a, N);
  alpha_h1<<<gridW, 256, 0, stream>>>(h_a, a3s, a3d, as_, ad_, hb, N);
  agg_h1_lin<<<gridW, 256, 0, stream>>>(hb, as_, ad_, offs, csr, b3, Wlin, blin, out, N);
}